// Round 2
// 222.583 us; speedup vs baseline: 1.0129x; 1.0129x over previous
//
#include <hip/hip_runtime.h>
#include <hip/hip_bf16.h>

#define SEQ 1024
#define DIM 128
#define NEG_SLOPE 0.1f

typedef __bf16 bf16x8 __attribute__((ext_vector_type(8)));
typedef float f32x4v __attribute__((ext_vector_type(4)));

// Phase-1 LDS: double-buffered {mask 64x64 bf16 (8KB) + nodes 128x64 bf16 (16KB)}.
// Row stride = 128 B = 8 x 16B units. Units are XOR-swizzled:
//   phys_unit = log_unit ^ f(row>>2),  f(x) = ((x&3)|((x&1)<<2)) ^ ((x>>2)&7)
// - ((x>>2)&7) spreads the transpose WRITES (lanes hit rows strided by 4;
//   any 16B-aligned stride alone aliases 16 lanes onto 2 banks -> was 8/16-way,
//   measured 12.6M conflict cycles). With the swizzle: 4-cycle optimum.
// - ((x&3)|((x&1)<<2)) spreads the 16-consecutive-row b128 READ groups over
//   all 8 units incl. bit2 -> reads stay at the 8-cycle optimum.
#define BUF_STRIDE 24576
#define NODES_OFF  8192

__device__ __forceinline__ int swz(int row, int unit) {
    const int x  = row >> 2;
    const int fx = ((x & 3) | ((x & 1) << 2)) ^ ((x >> 2) & 7);
    return row * 128 + ((unit ^ fx) << 4);
}

// Raw barrier: LDS-drain only. __syncthreads() emits s_waitcnt vmcnt(0) which
// drains the 2-chunk-deep register prefetch every chunk; global loads into
// private registers need no cross-wave ordering, only the ds ops do.
__device__ __forceinline__ void bar() {
    asm volatile("s_waitcnt lgkmcnt(0)" ::: "memory");
    __builtin_amdgcn_s_barrier();
    __builtin_amdgcn_sched_barrier(0);
}

__device__ __forceinline__ unsigned short bfb(float f) {
    __bf16 h = (__bf16)f;
    return __builtin_bit_cast(unsigned short, h);
}
__device__ __forceinline__ unsigned mpack(int x0, int x1) {
    unsigned m0 = (x0 != 0) ? 0x3F80u : 0u;   // bf16 1.0
    unsigned m1 = (x1 != 0) ? 0x3F80u : 0u;
    return m0 | (m1 << 16);
}

__global__ __launch_bounds__(256, 2)
void gcn_fused(const float* __restrict__ nodes,
               const int* __restrict__ adj,
               const float* __restrict__ W,
               const float* __restrict__ Bm,
               float* __restrict__ out)
{
    __shared__ alignas(16) unsigned char lds[2 * BUF_STRIDE];

    // XCD swizzle: all 16 m-tiles of a batch land on one XCD
    const int bid   = blockIdx.x;
    const int xcd   = bid & 7;
    const int slot  = bid >> 3;
    const int batch = ((slot >> 4) << 3) | xcd;   // [0,32)
    const int mtile = slot & 15;                  // [0,16)
    const int i0    = mtile << 6;

    const int tid  = threadIdx.x;
    const int wave = tid >> 6;
    const int lane = tid & 63;
    const int wm   = wave >> 1;
    const int wn   = wave & 1;
    const int lrow = lane & 15;
    const int quad = lane >> 4;

    const int*   __restrict__ adj_b   = adj   + (size_t)batch * SEQ * SEQ;
    const float* __restrict__ nodes_b = nodes + (size_t)batch * SEQ * DIM;

    // staging thread mapping (same coalesced global pattern as before)
    const int a_row = (tid >> 4) * 4;   // adj o-row group (4 consecutive rows)
    const int a_col = (tid & 15) * 4;   // adj i group (int4)
    const int n_row = (tid >> 5) * 4;   // nodes o-row group
    const int n_col = (tid & 31) * 4;   // nodes d group (float4)

    // swizzled write-column decomposition (loop-invariant)
    const int m_unit = (tid >> 4) >> 1;          // 16B unit of mask col
    const int m_sub  = ((tid >> 4) & 1) * 8;     // 8B half within unit
    const int n_unit = (tid >> 5) >> 1;          // + 4*it at use site
    const int n_sub  = ((tid >> 5) & 1) * 8;

    f32x4v acc[2][4] = {};
    f32x4v acc_cnt[2] = {};

    bf16x8 ones;
    #pragma unroll
    for (int j = 0; j < 8; ++j) ones[j] = __builtin_bit_cast(__bf16, (unsigned short)0x3F80);

    // two named register staging sets (static indexing only — no runtime-indexed
    // register arrays), giving a 2-chunk issue-to-consume prefetch window
    int4   A0[4], A1[4];
    float4 N0[8], N1[8];

    auto load_chunk = [&](int o0, int4 (&A)[4], float4 (&N)[8]) {
        const int* pa = adj_b + (size_t)(o0 + a_row) * SEQ + (i0 + a_col);
        #pragma unroll
        for (int r = 0; r < 4; ++r) A[r] = *(const int4*)(pa + (size_t)r * SEQ);
        const float* pn = nodes_b + (size_t)(o0 + n_row) * DIM + n_col;
        #pragma unroll
        for (int it = 0; it < 2; ++it)
            #pragma unroll
            for (int r = 0; r < 4; ++r)
                N[it * 4 + r] = *(const float4*)(pn + (size_t)(it * 32 + r) * DIM);
    };

    auto write_lds = [&](int base, const int4 (&A)[4], const float4 (&N)[8]) {
        unsigned char* mb = lds + base;
        unsigned char* nb = lds + base + NODES_OFF;
        #pragma unroll
        for (int j = 0; j < 4; ++j) {
            uint2 w;
            w.x = mpack(((const int*)&A[0])[j], ((const int*)&A[1])[j]);
            w.y = mpack(((const int*)&A[2])[j], ((const int*)&A[3])[j]);
            *(uint2*)(mb + swz(a_col + j, m_unit) + m_sub) = w;
        }
        #pragma unroll
        for (int it = 0; it < 2; ++it) {
            #pragma unroll
            for (int j = 0; j < 4; ++j) {
                uint2 w;
                w.x = (unsigned)bfb(((const float*)&N[it*4+0])[j]) |
                      ((unsigned)bfb(((const float*)&N[it*4+1])[j]) << 16);
                w.y = (unsigned)bfb(((const float*)&N[it*4+2])[j]) |
                      ((unsigned)bfb(((const float*)&N[it*4+3])[j]) << 16);
                *(uint2*)(nb + swz(n_col + j, 4 * it + n_unit) + n_sub) = w;
            }
        }
    };

    auto compute = [&](int base) {
        const unsigned char* mb = lds + base;
        const unsigned char* nb = lds + base + NODES_OFF;
        #pragma unroll
        for (int kk = 0; kk < 2; ++kk) {
            bf16x8 av[2], bv[4];
            av[0] = *(const bf16x8*)(mb + swz(wm * 32 +      lrow, 4 * kk + quad));
            av[1] = *(const bf16x8*)(mb + swz(wm * 32 + 16 + lrow, 4 * kk + quad));
            #pragma unroll
            for (int nf = 0; nf < 4; ++nf)
                bv[nf] = *(const bf16x8*)(nb + swz(wn * 64 + nf * 16 + lrow, 4 * kk + quad));
            #pragma unroll
            for (int mf = 0; mf < 2; ++mf) {
                #pragma unroll
                for (int nf = 0; nf < 4; ++nf)
                    acc[mf][nf] = __builtin_amdgcn_mfma_f32_16x16x32_bf16(av[mf], bv[nf], acc[mf][nf], 0, 0, 0);
                acc_cnt[mf] = __builtin_amdgcn_mfma_f32_16x16x32_bf16(av[mf], ones, acc_cnt[mf], 0, 0, 0);
            }
        }
    };

    // prologue: R0<-c0, R1<-c1; stage c0; R0<-c2  (2-deep in flight)
    load_chunk(0,   A0, N0);
    load_chunk(64,  A1, N1);
    write_lds(0, A0, N0);
    load_chunk(128, A0, N0);
    bar();

    // steady state, one raw barrier per chunk:
    //   compute(buf[c&1])  ||  stage buf[(c+1)&1] from R[(c+1)&1]  ||  issue load c+3
    for (int cc = 0; cc < 8; ++cc) {
        const int c0 = cc * 2;
        compute(0);
        write_lds(BUF_STRIDE, A1, N1);
        if (c0 + 3 < 16) load_chunk((c0 + 3) * 64, A1, N1);
        bar();
        compute(BUF_STRIDE);
        if (c0 + 2 < 16) write_lds(0, A0, N0);
        if (c0 + 4 < 16) load_chunk((c0 + 4) * 64, A0, N0);
        bar();
    }

    // poolsum -> pooled (divide by exact MFMA-computed in-degree), C-layout -> A-layout via LDS
    unsigned short (*pooled)[136] = (unsigned short (*)[136])(void*)lds;
    #pragma unroll
    for (int mf = 0; mf < 2; ++mf) {
        #pragma unroll
        for (int r = 0; r < 4; ++r) {
            const int row = wm * 32 + mf * 16 + quad * 4 + r;
            const float cnt = acc_cnt[mf][r];           // all columns equal = row count
            const float inv = (cnt > 0.5f) ? 1.0f / cnt : 0.0f;
            #pragma unroll
            for (int nf = 0; nf < 4; ++nf) {
                const int col = wn * 64 + nf * 16 + lrow;
                pooled[row][col] = bfb(acc[mf][nf][r] * inv);
            }
        }
    }
    __syncthreads();

    f32x4v acc2[2][4] = {};
    const int d_b0 = wn * 64 + lrow;

    // pooled @ W  (K=128)
    #pragma unroll
    for (int ks = 0; ks < 4; ++ks) {
        const int k0 = ks * 32 + quad * 8;
        bf16x8 av[2];
        #pragma unroll
        for (int mf = 0; mf < 2; ++mf)
            av[mf] = *(const bf16x8*)&pooled[wm * 32 + mf * 16 + lrow][k0];
        bf16x8 bv[4];
        const float* pw = W + (size_t)k0 * DIM + d_b0;
        #pragma unroll
        for (int nf = 0; nf < 4; ++nf) {
            #pragma unroll
            for (int j = 0; j < 8; ++j)
                bv[nf][j] = (__bf16)pw[j * DIM + nf * 16];
        }
        #pragma unroll
        for (int mf = 0; mf < 2; ++mf)
            #pragma unroll
            for (int nf = 0; nf < 4; ++nf)
                acc2[mf][nf] = __builtin_amdgcn_mfma_f32_16x16x32_bf16(av[mf], bv[nf], acc2[mf][nf], 0, 0, 0);
    }

    // nodes @ B  (K=128)
    #pragma unroll
    for (int ks = 0; ks < 4; ++ks) {
        const int k0 = ks * 32 + quad * 8;
        bf16x8 av[2];
        #pragma unroll
        for (int mf = 0; mf < 2; ++mf) {
            const float* p = nodes_b + (size_t)(i0 + wm * 32 + mf * 16 + lrow) * DIM + k0;
            const float4 f1 = *(const float4*)p;
            const float4 f2 = *(const float4*)(p + 4);
            av[mf][0] = (__bf16)f1.x; av[mf][1] = (__bf16)f1.y;
            av[mf][2] = (__bf16)f1.z; av[mf][3] = (__bf16)f1.w;
            av[mf][4] = (__bf16)f2.x; av[mf][5] = (__bf16)f2.y;
            av[mf][6] = (__bf16)f2.z; av[mf][7] = (__bf16)f2.w;
        }
        bf16x8 bv[4];
        const float* pB = Bm + (size_t)k0 * DIM + d_b0;
        #pragma unroll
        for (int nf = 0; nf < 4; ++nf) {
            #pragma unroll
            for (int j = 0; j < 8; ++j)
                bv[nf][j] = (__bf16)pB[j * DIM + nf * 16];
        }
        #pragma unroll
        for (int mf = 0; mf < 2; ++mf)
            #pragma unroll
            for (int nf = 0; nf < 4; ++nf)
                acc2[mf][nf] = __builtin_amdgcn_mfma_f32_16x16x32_bf16(av[mf], bv[nf], acc2[mf][nf], 0, 0, 0);
    }

    // leaky-relu + store
    float* out_b = out + (size_t)batch * SEQ * DIM;
    #pragma unroll
    for (int mf = 0; mf < 2; ++mf) {
        #pragma unroll
        for (int nf = 0; nf < 4; ++nf) {
            const int col = wn * 64 + nf * 16 + lrow;
            #pragma unroll
            for (int r = 0; r < 4; ++r) {
                const int row = i0 + wm * 32 + mf * 16 + quad * 4 + r;
                const float x = acc2[mf][nf][r];
                out_b[(size_t)row * DIM + col] = (x > 0.0f) ? x : NEG_SLOPE * x;
            }
        }
    }
}

extern "C" void kernel_launch(void* const* d_in, const int* in_sizes, int n_in,
                              void* d_out, int out_size, void* d_ws, size_t ws_size,
                              hipStream_t stream) {
    const float* nodes = (const float*)d_in[0];
    const int*   adj   = (const int*)d_in[1];
    const float* W     = (const float*)d_in[2];
    const float* Bm    = (const float*)d_in[3];
    float*       out   = (float*)d_out;
    gcn_fused<<<dim3(512), dim3(256), 0, stream>>>(nodes, adj, W, Bm, out);
}